// Round 14
// baseline (333.092 us; speedup 1.0000x reference)
//
#include <hip/hip_runtime.h>

// Mixture-of-Experts, sparse top-2.
// Round 14: r13 (best, 332us) + prep residency fix: bf16 LDS staging
// (16KB/block -> 8 blocks/CU vs 5) and flat exact grid (no dead blocks).
// GEMM/LN/comb/route byte-identical to r13.

#define E_N 8
#define TOPK 2
#define DM 1024
#define FF 4096
#define NTOK 4096
#define NA 8192
#define LN_EPS 1e-5f
#define NBX 128   // persistent blocks per XCD (1024 total / 8)

typedef __attribute__((ext_vector_type(4))) float f32x4;
typedef __attribute__((ext_vector_type(8))) short short8;

__device__ __forceinline__ unsigned short f2bf(float f) {
    unsigned int u = __builtin_bit_cast(unsigned int, f);
    u = (u + 0x7FFFu + ((u >> 16) & 1u)) >> 16;   // RNE
    return (unsigned short)u;
}
__device__ __forceinline__ float bf2f(unsigned short h) {
    unsigned int u = ((unsigned int)h) << 16;
    return __builtin_bit_cast(float, u);
}
__device__ __forceinline__ void unp(unsigned int u, float& lo, float& hi) {
    lo = bf2f((unsigned short)(u & 0xffffu));
    hi = bf2f((unsigned short)(u >> 16));
}
__device__ __forceinline__ unsigned int pk(float lo, float hi) {
    return (unsigned int)f2bf(lo) | ((unsigned int)f2bf(hi) << 16);
}

__device__ __forceinline__ void gload16(const unsigned short* g, unsigned short* lds) {
    __builtin_amdgcn_global_load_lds(
        (const __attribute__((address_space(1))) unsigned int*)g,
        (__attribute__((address_space(3))) unsigned int*)lds, 16, 0, 0);
}

// ---- build one GEMM-ready B-tile (16KB contiguous) from f32 weights.
// Tile image (same as r13, verified): row r (n-local 0..127), phys granule p
// holds logical k-granule p^(r&7):
//   out[r*64 + p*8 + ee] = bf16( src[ ((p^(r&7))*8 + ee)*sld + r ] )
// bf16 LDS staging: t16[k*128 + (n ^ ((k&7)<<2))] = bf16(src[k][n]).
// phase2 reads t16[k*128 + (r ^ (e<<2))], k=(g^(r&7))*8+e -> element (k, r).
__device__ __forceinline__ void make_btile(const float* __restrict__ s, int sld,
                                           unsigned short* __restrict__ out,
                                           unsigned short* t16) {
    int tid = threadIdx.x;
    int krow = tid >> 5, n0 = (tid & 31) * 4;
    float4 v[8];
#pragma unroll
    for (int p = 0; p < 8; p++)
        v[p] = *(const float4*)(s + (size_t)(krow + p * 8) * sld + n0);
#pragma unroll
    for (int p = 0; p < 8; p++) {
        int k = krow + p * 8;
        uint2 w; w.x = pk(v[p].x, v[p].y); w.y = pk(v[p].z, v[p].w);
        *(uint2*)&t16[k * 128 + (n0 ^ ((k & 7) << 2))] = w;
    }
    __syncthreads();
    int r = tid >> 1, gh = (tid & 1) * 4;
    unsigned int ov[16];
#pragma unroll
    for (int i = 0; i < 4; i++) {
        int kb = ((gh + i) ^ (r & 7)) << 3;
#pragma unroll
        for (int e = 0; e < 8; e += 2) {
            unsigned short lo = t16[(kb + e) * 128 + (r ^ (e << 2))];
            unsigned short hi = t16[(kb + e + 1) * 128 + (r ^ ((e + 1) << 2))];
            ov[i * 4 + (e >> 1)] = (unsigned int)lo | ((unsigned int)hi << 16);
        }
    }
    unsigned short* dp = out + (size_t)r * 64 + gh * 8;
#pragma unroll
    for (int i = 0; i < 4; i++)
        *(uint4*)(dp + i * 8) = *(uint4*)&ov[i * 4];
}

// ---------------- prep: flat grid. blocks [0,4096) W1 tiles, [4096,8192) W2
// tiles, [8192,9216) router. -------------------------------------------------

__global__ __launch_bounds__(256) void k_prep(
        const float* __restrict__ W1, const float* __restrict__ W2,
        unsigned short* __restrict__ W1T, unsigned short* __restrict__ W2T,
        const float* __restrict__ x, const float* __restrict__ Wr,
        const float* __restrict__ br, unsigned short* __restrict__ xb,
        int* __restrict__ topk_idx, float* __restrict__ topk_p)
{
    __shared__ unsigned short t16[64 * 128];   // 16KB
    int bid = blockIdx.x;
    int tid = threadIdx.x;

    if (bid >= 8192) {
        // router: 4 tokens/block (one per wave), fused x->bf16, vectorized
        int blk = bid - 8192;
        int wv = tid >> 6, lane = tid & 63;
        int t = blk * 4 + wv;
        const float* xr = x + (size_t)t * DM;
        unsigned short* xbr = xb + (size_t)t * DM;
        float4 xv[4];
#pragma unroll
        for (int p = 0; p < 4; p++)
            xv[p] = *(const float4*)(xr + p * 256 + lane * 4);
#pragma unroll
        for (int p = 0; p < 4; p++) {
            uint2 pkd; pkd.x = pk(xv[p].x, xv[p].y); pkd.y = pk(xv[p].z, xv[p].w);
            *(uint2*)(xbr + p * 256 + lane * 4) = pkd;
        }
        float a0=0,a1=0,a2=0,a3=0,a4=0,a5=0,a6=0,a7=0;
#pragma unroll
        for (int p = 0; p < 4; p++) {
            int d0 = p * 256 + lane * 4;
            float xs[4] = {xv[p].x, xv[p].y, xv[p].z, xv[p].w};
#pragma unroll
            for (int j = 0; j < 4; j++) {
                const float4* wp = (const float4*)(Wr + (d0 + j) * 8);
                float4 w0 = wp[0], w1 = wp[1];
                a0 += xs[j] * w0.x; a1 += xs[j] * w0.y; a2 += xs[j] * w0.z; a3 += xs[j] * w0.w;
                a4 += xs[j] * w1.x; a5 += xs[j] * w1.y; a6 += xs[j] * w1.z; a7 += xs[j] * w1.w;
            }
        }
#pragma unroll
        for (int off = 32; off; off >>= 1) {
            a0 += __shfl_xor(a0, off); a1 += __shfl_xor(a1, off);
            a2 += __shfl_xor(a2, off); a3 += __shfl_xor(a3, off);
            a4 += __shfl_xor(a4, off); a5 += __shfl_xor(a5, off);
            a6 += __shfl_xor(a6, off); a7 += __shfl_xor(a7, off);
        }
        if (lane == 0) {
            float l[8] = {a0 + br[0], a1 + br[1], a2 + br[2], a3 + br[3],
                          a4 + br[4], a5 + br[5], a6 + br[6], a7 + br[7]};
            int i0 = 0;
#pragma unroll
            for (int e = 1; e < 8; e++) if (l[e] > l[i0]) i0 = e;
            int i1 = (i0 == 0) ? 1 : 0;
#pragma unroll
            for (int e = 0; e < 8; e++) if (e != i0 && l[e] > l[i1]) i1 = e;
            float p1 = expf(l[i1] - l[i0]);
            float s = 1.0f + p1;
            topk_idx[2 * t]     = i0;
            topk_idx[2 * t + 1] = i1;
            topk_p[2 * t]       = 1.0f / s;
            topk_p[2 * t + 1]   = p1 / s;
        }
        return;
    }

    if (bid < 4096) {
        // W1 expert z = bid>>9: nt = (bid>>4)&31 (over F), kt = bid&15 (over D)
        int z = bid >> 9, nt = (bid >> 4) & 31, kt = bid & 15;
        make_btile(W1 + (size_t)z * DM * FF + (size_t)(kt * 64) * FF + nt * 128, FF,
                   W1T + (((size_t)z * 32 + nt) * 16 + kt) * 8192, t16);
    } else {
        // W2 expert e = (bid-4096)>>9: nt = (bid>>6)&7 (over D), kt = bid&63 (over F)
        int b = bid - 4096;
        int e = b >> 9, nt = (b >> 6) & 7, kt = b & 63;
        make_btile(W2 + (size_t)e * FF * DM + (size_t)(kt * 64) * DM + nt * 128, DM,
                   W2T + (((size_t)e * 8 + nt) * 64 + kt) * 8192, t16);
    }
}

// ---------------- route: histogram + prefix + scatter, one block ------------

__global__ __launch_bounds__(256) void k_route2(const int* __restrict__ topk_idx,
        int* __restrict__ cnt, int* __restrict__ offs,
        int* __restrict__ assign_tok, int* __restrict__ assign_e,
        int* __restrict__ slot)
{
    __shared__ int h[8], base[8];
    int tid = threadIdx.x;
    if (tid < 8) h[tid] = 0;
    __syncthreads();
    int el[32];
#pragma unroll
    for (int i = 0; i < 32; i++) {
        int idx = tid * 32 + i;
        el[i] = topk_idx[idx];
        atomicAdd(&h[el[i]], 1);
    }
    __syncthreads();
    if (tid == 0) {
        int s = 0;
        for (int e = 0; e < E_N; e++) { offs[e] = s; cnt[e] = h[e]; base[e] = s; s += h[e]; }
        offs[E_N] = s;
    }
    __syncthreads();
    if (tid < 8) h[tid] = base[tid];
    __syncthreads();
#pragma unroll
    for (int i = 0; i < 32; i++) {
        int idx = tid * 32 + i;
        int e = el[i];
        int pos = atomicAdd(&h[e], 1);
        assign_tok[pos] = idx >> 1;
        assign_e[pos] = e;
        slot[idx] = pos;
    }
}

// ---------------- persistent grouped GEMM, 128x128, 4 waves, m97 K-loop -----
// B from pre-swizzled 16KB tiles [e][NT][KT] (linear image copy); A staged
// with inverse-swizzled source column. Expert->XCD pinning e = bid&7.

template<bool GATHER, bool EPI>
__global__ __launch_bounds__(256, 4) void k_gemm(
    const unsigned short* __restrict__ A,
    const unsigned short* __restrict__ BT,   // tiled
    const float* __restrict__ bias,
    unsigned short* __restrict__ C,
    const int* __restrict__ cnt, const int* __restrict__ offs,
    const int* __restrict__ gather_tok,
    int Kslice, int N, int ldA, int NT, int KT, int GX, int KS, size_t slicePitch)
{
    __shared__ __align__(1024) char lds[32768];   // A 16KB | B 16KB

    int bid = blockIdx.x;
    int e = bid & 7;                 // expert == XCD
    int lb = bid >> 3;
    int M = cnt[e];
    if (M <= 0) return;
    int off_e = offs[e];
    int nrows = (M + 127) >> 7;
    int ntiles = nrows * GX * KS;

    int tid = threadIdx.x;
    int wv = tid >> 6, lane = tid & 63;
    int lr = lane & 15, hi = lane >> 4;
    int mW = (wv >> 1) * 64, nW = (wv & 1) * 64;
    int colsw = ((lane & 7) ^ (lane >> 3)) * 8;
    int l3 = lane >> 3;
    int nt = Kslice >> 6;

    for (int t = lb; t < ntiles; t += NBX) {
        int r = t % nrows;
        int q = t / nrows;
        int xn = q % GX;
        int ks = q / GX;
        int m0 = r * 128;
        int n0 = xn * 128;
        int kbase = ks * Kslice;

        const unsigned short* aptr[4];
        const unsigned short* bptr[4];
        size_t btile = ((size_t)(e * NT + xn) * KT + (size_t)ks * nt) * 8192;
#pragma unroll
        for (int i = 0; i < 4; i++) {
            int j = wv * 4 + i;
            int rr = m0 + j * 8 + l3; rr = (rr < M) ? rr : (M - 1);
            size_t arow = GATHER ? (size_t)gather_tok[off_e + rr] : (size_t)(off_e + rr);
            aptr[i] = A + arow * (size_t)ldA + kbase + colsw;
            bptr[i] = BT + btile + j * 512 + lane * 8;   // linear tile image
        }

        f32x4 acc[4][4];
        f32x4 zz = {0.f, 0.f, 0.f, 0.f};
#pragma unroll
        for (int mi = 0; mi < 4; mi++)
#pragma unroll
            for (int ni = 0; ni < 4; ni++) acc[mi][ni] = zz;

        for (int kt = 0; kt < nt; ++kt) {
            __syncthreads();                  // prev tile fully consumed
#pragma unroll
            for (int i = 0; i < 4; i++) {
                gload16(aptr[i] + kt * 64, (unsigned short*)(lds + (wv * 4 + i) * 1024));
                gload16(bptr[i] + (size_t)kt * 8192,
                        (unsigned short*)(lds + 16384 + (wv * 4 + i) * 1024));
            }
            __syncthreads();                  // drains vmcnt before barrier
#pragma unroll
            for (int kss = 0; kss < 2; kss++) {
                int cb = (kss * 64 + hi * 16) ^ ((lr & 7) << 4);
                short8 afr[4], bfr[4];
#pragma unroll
                for (int ni = 0; ni < 4; ni++)
                    bfr[ni] = *(const short8*)(lds + 16384 + (nW + ni * 16 + lr) * 128 + cb);
#pragma unroll
                for (int mi = 0; mi < 4; mi++)
                    afr[mi] = *(const short8*)(lds + (mW + mi * 16 + lr) * 128 + cb);
                __builtin_amdgcn_s_setprio(1);
#pragma unroll
                for (int mi = 0; mi < 4; mi++)
#pragma unroll
                    for (int ni = 0; ni < 4; ni++)
                        acc[mi][ni] = __builtin_amdgcn_mfma_f32_16x16x32_bf16(
                            afr[mi], bfr[ni], acc[mi][ni], 0, 0, 0);
                __builtin_amdgcn_s_setprio(0);
            }
        }

        unsigned short* Cs = C + ks * slicePitch;
        float bv[4] = {0.f, 0.f, 0.f, 0.f};
        if (EPI) {
#pragma unroll
            for (int ni = 0; ni < 4; ni++)
                bv[ni] = bias[(size_t)e * N + (n0 + nW + ni * 16 + lr)];
        }
#pragma unroll
        for (int mi = 0; mi < 4; mi++) {
            int mb = m0 + mW + mi * 16 + hi * 4;
#pragma unroll
            for (int rr = 0; rr < 4; rr++) {
                int m = mb + rr;
                if (m < M) {
                    unsigned short* crow = Cs + (size_t)(off_e + m) * N;
#pragma unroll
                    for (int ni = 0; ni < 4; ni++) {
                        float v = acc[mi][ni][rr];
                        if (EPI) v = fmaxf(v + bv[ni], 0.0f);
                        crow[n0 + nW + ni * 16 + lr] = f2bf(v);
                    }
                }
            }
        }
    }
}

// ---------------- LN1 over F, in-place ----------------

__global__ __launch_bounds__(256) void k_ln1(unsigned short* __restrict__ H,
        const float* __restrict__ g, const float* __restrict__ b,
        const int* __restrict__ assign_e)
{
    size_t a = blockIdx.x;
    int e = assign_e[a];
    unsigned short* row = H + a * FF;
    int tid = threadIdx.x;
    uint4 u0 = *(const uint4*)(row + tid * 16);
    uint4 u1 = *(const uint4*)(row + tid * 16 + 8);
    float v[16];
    unp(u0.x, v[0], v[1]);  unp(u0.y, v[2], v[3]);
    unp(u0.z, v[4], v[5]);  unp(u0.w, v[6], v[7]);
    unp(u1.x, v[8], v[9]);  unp(u1.y, v[10], v[11]);
    unp(u1.z, v[12], v[13]); unp(u1.w, v[14], v[15]);
    float s = 0.f, q = 0.f;
#pragma unroll
    for (int i = 0; i < 16; i++) { s += v[i]; q += v[i] * v[i]; }
#pragma unroll
    for (int off = 32; off; off >>= 1) { s += __shfl_xor(s, off); q += __shfl_xor(q, off); }
    __shared__ float red[8];
    int wv = tid >> 6, lane = tid & 63;
    if (lane == 0) { red[wv * 2] = s; red[wv * 2 + 1] = q; }
    __syncthreads();
    s = red[0] + red[2] + red[4] + red[6];
    q = red[1] + red[3] + red[5] + red[7];
    float mu = s * (1.0f / FF);
    float var = q * (1.0f / FF) - mu * mu;
    float rstd = rsqrtf(var + LN_EPS);
    const float* gg = g + (size_t)e * FF + tid * 16;
    const float* bb = b + (size_t)e * FF + tid * 16;
    float4 G0 = *(const float4*)(gg);      float4 G1 = *(const float4*)(gg + 4);
    float4 G2 = *(const float4*)(gg + 8);  float4 G3 = *(const float4*)(gg + 12);
    float4 B0 = *(const float4*)(bb);      float4 B1 = *(const float4*)(bb + 4);
    float4 B2 = *(const float4*)(bb + 8);  float4 B3 = *(const float4*)(bb + 12);
    float gvv[16] = {G0.x,G0.y,G0.z,G0.w,G1.x,G1.y,G1.z,G1.w,G2.x,G2.y,G2.z,G2.w,G3.x,G3.y,G3.z,G3.w};
    float bvv[16] = {B0.x,B0.y,B0.z,B0.w,B1.x,B1.y,B1.z,B1.w,B2.x,B2.y,B2.z,B2.w,B3.x,B3.y,B3.z,B3.w};
#pragma unroll
    for (int i = 0; i < 16; i++) v[i] = (v[i] - mu) * rstd * gvv[i] + bvv[i];
    u0.x = pk(v[0], v[1]);  u0.y = pk(v[2], v[3]);
    u0.z = pk(v[4], v[5]);  u0.w = pk(v[6], v[7]);
    u1.x = pk(v[8], v[9]);  u1.y = pk(v[10], v[11]);
    u1.z = pk(v[12], v[13]); u1.w = pk(v[14], v[15]);
    *(uint4*)(row + tid * 16) = u0;
    *(uint4*)(row + tid * 16 + 8) = u1;
}

// ---------------- combine: sum split-K partials + bias + relu + LN2 + gate --

__global__ __launch_bounds__(256) void k_comb(const unsigned short* __restrict__ Yp,
        const float* __restrict__ g, const float* __restrict__ b2,
        const float* __restrict__ be,
        const int* __restrict__ slot, const float* __restrict__ topk_p,
        const int* __restrict__ assign_e, float* __restrict__ out)
{
    int t = blockIdx.x;
    int s0 = slot[2 * t], s1 = slot[2 * t + 1];
    float p0 = topk_p[2 * t], p1 = topk_p[2 * t + 1];
    int e0 = assign_e[s0], e1 = assign_e[s1];
    int tid = threadIdx.x;
    int d = tid * 4;
    const unsigned short* Y1 = Yp + (size_t)NA * DM;
    uint2 ua0 = *(const uint2*)(Yp + (size_t)s0 * DM + d);
    uint2 ua1 = *(const uint2*)(Y1 + (size_t)s0 * DM + d);
    uint2 ub0 = *(const uint2*)(Yp + (size_t)s1 * DM + d);
    uint2 ub1 = *(const uint2*)(Y1 + (size_t)s1 * DM + d);
    float4 bza = *(const float4*)(b2 + (size_t)e0 * DM + d);
    float4 bzb = *(const float4*)(b2 + (size_t)e1 * DM + d);
    float x0, x1, y0, y1;
    float va[4], vb[4];
    unp(ua0.x, x0, x1); unp(ua1.x, y0, y1);
    va[0] = fmaxf(x0 + y0 + bza.x, 0.f); va[1] = fmaxf(x1 + y1 + bza.y, 0.f);
    unp(ua0.y, x0, x1); unp(ua1.y, y0, y1);
    va[2] = fmaxf(x0 + y0 + bza.z, 0.f); va[3] = fmaxf(x1 + y1 + bza.w, 0.f);
    unp(ub0.x, x0, x1); unp(ub1.x, y0, y1);
    vb[0] = fmaxf(x0 + y0 + bzb.x, 0.f); vb[1] = fmaxf(x1 + y1 + bzb.y, 0.f);
    unp(ub0.y, x0, x1); unp(ub1.y, y0, y1);
    vb[2] = fmaxf(x0 + y0 + bzb.z, 0.f); vb[3] = fmaxf(x1 + y1 + bzb.w, 0.f);

    float sa = 0.f, qa = 0.f, sb = 0.f, qb = 0.f;
#pragma unroll
    for (int i = 0; i < 4; i++) {
        sa += va[i]; qa += va[i] * va[i];
        sb += vb[i]; qb += vb[i] * vb[i];
    }
#pragma unroll
    for (int off = 32; off; off >>= 1) {
        sa += __shfl_xor(sa, off); qa += __shfl_xor(qa, off);
        sb += __shfl_xor(sb, off); qb += __shfl_xor(qb, off);
    }
    __shared__ float red[16];
    int wv = tid >> 6, lane = tid & 63;
    if (lane == 0) { red[wv*4+0]=sa; red[wv*4+1]=qa; red[wv*4+2]=sb; red[wv*4+3]=qb; }
    __syncthreads();
    sa = red[0] + red[4] + red[8]  + red[12];
    qa = red[1] + red[5] + red[9]  + red[13];
    sb = red[2] + red[6] + red[10] + red[14];
    qb = red[3] + red[7] + red[11] + red[15];
    float mua = sa * (1.0f / DM), vara = qa * (1.0f / DM) - mua * mua;
    float ra = rsqrtf(vara + LN_EPS);
    float mub = sb * (1.0f / DM), varb = qb * (1.0f / DM) - mub * mub;
    float rb = rsqrtf(varb + LN_EPS);
    float4 ga  = *(const float4*)(g + (size_t)e0 * DM + d);
    float4 ba  = *(const float4*)(be + (size_t)e0 * DM + d);
    float4 gb4 = *(const float4*)(g + (size_t)e1 * DM + d);
    float4 bb4 = *(const float4*)(be + (size_t)e1 * DM + d);
    float4 o;
    o.x = p0 * ((va[0] - mua) * ra * ga.x + ba.x) + p1 * ((vb[0] - mub) * rb * gb4.x + bb4.x);
    o.y = p0 * ((va[1] - mua) * ra * ga.y + ba.y) + p1 * ((vb[1] - mub) * rb * gb4.y + bb4.y);
    o.z = p0 * ((va[2] - mua) * ra * ga.z + ba.z) + p1 * ((vb[2] - mub) * rb * gb4.z + bb4.z);
    o.w = p0 * ((va[3] - mua) * ra * ga.w + ba.w) + p1 * ((vb[3] - mub) * rb * gb4.w + bb4.w);
    *(float4*)(out + (size_t)t * DM + d) = o;
}

// ---------------- launch ----------------

extern "C" void kernel_launch(void* const* d_in, const int* in_sizes, int n_in,
                              void* d_out, int out_size, void* d_ws, size_t ws_size,
                              hipStream_t stream) {
    const float* x   = (const float*)d_in[0];
    const float* Wr  = (const float*)d_in[1];
    const float* br  = (const float*)d_in[2];
    const float* W1  = (const float*)d_in[3];
    const float* b1  = (const float*)d_in[4];
    const float* g1  = (const float*)d_in[5];
    const float* be1 = (const float*)d_in[6];
    const float* W2  = (const float*)d_in[7];
    const float* b2  = (const float*)d_in[8];
    const float* g2  = (const float*)d_in[9];
    const float* be2 = (const float*)d_in[10];
    float* out = (float*)d_out;

    char* w = (char*)d_ws;
    int*   cnt        = (int*)(w);
    int*   offs       = (int*)(w + 128);
    int*   topk_idx   = (int*)(w + 512);
    float* topk_p     = (float*)(w + 512 + (32 << 10));
    int*   assign_tok = (int*)(w + 512 + (64 << 10));
    int*   assign_e   = (int*)(w + 512 + (96 << 10));
    int*   slot       = (int*)(w + 512 + (128 << 10));
    unsigned short* xb  = (unsigned short*)(w + ((size_t)1 << 20));
    unsigned short* W1T = (unsigned short*)(w + ((size_t)9 << 20));    // tiled, 64MB
    unsigned short* W2T = (unsigned short*)(w + ((size_t)73 << 20));   // tiled, 64MB
    unsigned short* Hb  = (unsigned short*)(w + ((size_t)137 << 20));  // [NA][F] bf16
    unsigned short* Yp  = (unsigned short*)(w + ((size_t)201 << 20));  // [2][NA][D] bf16

    // prep: flat grid — 4096 W1 tiles, 4096 W2 tiles, 1024 router blocks
    k_prep<<<9216, 256, 0, stream>>>(
        W1, W2, W1T, W2T, x, Wr, br, xb, topk_idx, topk_p);
    k_route2<<<1, 256, 0, stream>>>(topk_idx, cnt, offs, assign_tok, assign_e, slot);
    // GEMM1: gathered x rows x W1T(tiled) -> Hb(+bias,relu); K=1024, NT=32 KT=16
    k_gemm<true, true><<<8 * NBX, 256, 0, stream>>>(
        xb, W1T, b1, Hb, cnt, offs, assign_tok, DM, FF, DM, 32, 16, 32, 1, 0);
    k_ln1<<<NA, 256, 0, stream>>>(Hb, g1, be1, assign_e);
    // GEMM2: Hb x W2T(tiled) -> Yp partials; Kslice=2048, NT=8 KT=64, KS=2
    k_gemm<false, false><<<8 * NBX, 256, 0, stream>>>(
        Hb, W2T, nullptr, Yp, cnt, offs, nullptr, FF / 2, DM, FF, 8, 64, 8, 2,
        (size_t)NA * DM);
    k_comb<<<NTOK, 256, 0, stream>>>(Yp, g2, b2, be2, slot, topk_p, assign_e, out);
}

// Round 15
// 330.468 us; speedup vs baseline: 1.0079x; 1.0079x over previous
//
#include <hip/hip_runtime.h>

// Mixture-of-Experts, sparse top-2.
// Round 15: r13 (best, 332us) with ONE change — prep phase-1 staging via
// global_load_lds (async direct-to-LDS, Common-mistake #1 applied to prep).
// Phase-2 tile-image builder, GEMMs (tiled pre-swizzled B), LN1, comb, route
// are r13-verbatim.

#define E_N 8
#define TOPK 2
#define DM 1024
#define FF 4096
#define NTOK 4096
#define NA 8192
#define LN_EPS 1e-5f
#define NBX 128   // persistent blocks per XCD (1024 total / 8)

typedef __attribute__((ext_vector_type(4))) float f32x4;
typedef __attribute__((ext_vector_type(8))) short short8;

__device__ __forceinline__ unsigned short f2bf(float f) {
    unsigned int u = __builtin_bit_cast(unsigned int, f);
    u = (u + 0x7FFFu + ((u >> 16) & 1u)) >> 16;   // RNE
    return (unsigned short)u;
}
__device__ __forceinline__ float bf2f(unsigned short h) {
    unsigned int u = ((unsigned int)h) << 16;
    return __builtin_bit_cast(float, u);
}
__device__ __forceinline__ void unp(unsigned int u, float& lo, float& hi) {
    lo = bf2f((unsigned short)(u & 0xffffu));
    hi = bf2f((unsigned short)(u >> 16));
}
__device__ __forceinline__ unsigned int pk(float lo, float hi) {
    return (unsigned int)f2bf(lo) | ((unsigned int)f2bf(hi) << 16);
}

__device__ __forceinline__ void gload16(const unsigned short* g, unsigned short* lds) {
    __builtin_amdgcn_global_load_lds(
        (const __attribute__((address_space(1))) unsigned int*)g,
        (__attribute__((address_space(3))) unsigned int*)lds, 16, 0, 0);
}

// ---- build one GEMM-ready B-tile (16KB contiguous) from f32 weights.
// Tile image (r13, verified): row r (n-local 0..127), phys 16B-granule p
// holds logical k-granule p^(r&7):
//   out[r*64 + p*8 + ee] = bf16( src[ ((p^(r&7))*8 + ee)*sld + r ] )
// phase1: 32x global_load_lds(16B) -> linear f32 LDS tile [64 k][128 n]
//   instr j (wave-uniform dst tile+j*256): lane l loads f32[k= j*2+(l>>5)]
//   [n=(l&31)*4 ..+3]  -- async, no VGPR round trip.
// phase2 (r13-verbatim): column reads (2-way banks, free), pack, 64B stores.
__device__ __forceinline__ void make_btile(const float* __restrict__ s, int sld,
                                           unsigned short* __restrict__ out,
                                           float* tile) {
    int tid = threadIdx.x;
    int wv = tid >> 6, lane = tid & 63;
    int kl = lane >> 5;               // 0/1: which k-row within the instr
    int n = (lane & 31) * 4;
#pragma unroll
    for (int i = 0; i < 8; i++) {
        int j = wv * 8 + i;
        int k = j * 2 + kl;
        gload16((const unsigned short*)(s + (size_t)k * sld + n),
                (unsigned short*)(tile + j * 256));
    }
    __syncthreads();   // drains vmcnt (global_load_lds) before phase 2
    int r = tid >> 1, gh = (tid & 1) * 4;
    const float* col = tile + r;
    unsigned int ov[16];
#pragma unroll
    for (int i = 0; i < 4; i++) {
        int kb = ((gh + i) ^ (r & 7)) << 3;
#pragma unroll
        for (int ee = 0; ee < 8; ee += 2)
            ov[i * 4 + (ee >> 1)] = pk(col[(kb + ee) * 128], col[(kb + ee + 1) * 128]);
    }
    unsigned short* dp = out + (size_t)r * 64 + gh * 8;
#pragma unroll
    for (int i = 0; i < 4; i++)
        *(uint4*)(dp + i * 8) = *(uint4*)&ov[i * 4];
}

// ---------------- prep: flat grid. [0,4096) W1 tiles, [4096,8192) W2 tiles,
// [8192,9216) router. --------------------------------------------------------

__global__ __launch_bounds__(256) void k_prep(
        const float* __restrict__ W1, const float* __restrict__ W2,
        unsigned short* __restrict__ W1T, unsigned short* __restrict__ W2T,
        const float* __restrict__ x, const float* __restrict__ Wr,
        const float* __restrict__ br, unsigned short* __restrict__ xb,
        int* __restrict__ topk_idx, float* __restrict__ topk_p)
{
    __shared__ float tile[64 * 128];   // 32KB
    int bid = blockIdx.x;
    int tid = threadIdx.x;

    if (bid >= 8192) {
        // router: 4 tokens/block (one per wave), fused x->bf16, vectorized
        int blk = bid - 8192;
        int wv = tid >> 6, lane = tid & 63;
        int t = blk * 4 + wv;
        const float* xr = x + (size_t)t * DM;
        unsigned short* xbr = xb + (size_t)t * DM;
        float4 xv[4];
#pragma unroll
        for (int p = 0; p < 4; p++)
            xv[p] = *(const float4*)(xr + p * 256 + lane * 4);
#pragma unroll
        for (int p = 0; p < 4; p++) {
            uint2 pkd; pkd.x = pk(xv[p].x, xv[p].y); pkd.y = pk(xv[p].z, xv[p].w);
            *(uint2*)(xbr + p * 256 + lane * 4) = pkd;
        }
        float a0=0,a1=0,a2=0,a3=0,a4=0,a5=0,a6=0,a7=0;
#pragma unroll
        for (int p = 0; p < 4; p++) {
            int d0 = p * 256 + lane * 4;
            float xs[4] = {xv[p].x, xv[p].y, xv[p].z, xv[p].w};
#pragma unroll
            for (int j = 0; j < 4; j++) {
                const float4* wp = (const float4*)(Wr + (d0 + j) * 8);
                float4 w0 = wp[0], w1 = wp[1];
                a0 += xs[j] * w0.x; a1 += xs[j] * w0.y; a2 += xs[j] * w0.z; a3 += xs[j] * w0.w;
                a4 += xs[j] * w1.x; a5 += xs[j] * w1.y; a6 += xs[j] * w1.z; a7 += xs[j] * w1.w;
            }
        }
#pragma unroll
        for (int off = 32; off; off >>= 1) {
            a0 += __shfl_xor(a0, off); a1 += __shfl_xor(a1, off);
            a2 += __shfl_xor(a2, off); a3 += __shfl_xor(a3, off);
            a4 += __shfl_xor(a4, off); a5 += __shfl_xor(a5, off);
            a6 += __shfl_xor(a6, off); a7 += __shfl_xor(a7, off);
        }
        if (lane == 0) {
            float l[8] = {a0 + br[0], a1 + br[1], a2 + br[2], a3 + br[3],
                          a4 + br[4], a5 + br[5], a6 + br[6], a7 + br[7]};
            int i0 = 0;
#pragma unroll
            for (int e = 1; e < 8; e++) if (l[e] > l[i0]) i0 = e;
            int i1 = (i0 == 0) ? 1 : 0;
#pragma unroll
            for (int e = 0; e < 8; e++) if (e != i0 && l[e] > l[i1]) i1 = e;
            float p1 = expf(l[i1] - l[i0]);
            float s = 1.0f + p1;
            topk_idx[2 * t]     = i0;
            topk_idx[2 * t + 1] = i1;
            topk_p[2 * t]       = 1.0f / s;
            topk_p[2 * t + 1]   = p1 / s;
        }
        return;
    }

    if (bid < 4096) {
        // W1 expert z = bid>>9: nt = (bid>>4)&31 (over F), kt = bid&15 (over D)
        int z = bid >> 9, nt = (bid >> 4) & 31, kt = bid & 15;
        make_btile(W1 + (size_t)z * DM * FF + (size_t)(kt * 64) * FF + nt * 128, FF,
                   W1T + (((size_t)z * 32 + nt) * 16 + kt) * 8192, tile);
    } else {
        // W2 expert e = (bid-4096)>>9: nt = (bid>>6)&7 (over D), kt = bid&63 (over F)
        int b = bid - 4096;
        int e = b >> 9, nt = (b >> 6) & 7, kt = b & 63;
        make_btile(W2 + (size_t)e * FF * DM + (size_t)(kt * 64) * DM + nt * 128, DM,
                   W2T + (((size_t)e * 8 + nt) * 64 + kt) * 8192, tile);
    }
}

// ---------------- route: histogram + prefix + scatter, one block ------------

__global__ __launch_bounds__(256) void k_route2(const int* __restrict__ topk_idx,
        int* __restrict__ cnt, int* __restrict__ offs,
        int* __restrict__ assign_tok, int* __restrict__ assign_e,
        int* __restrict__ slot)
{
    __shared__ int h[8], base[8];
    int tid = threadIdx.x;
    if (tid < 8) h[tid] = 0;
    __syncthreads();
    int el[32];
#pragma unroll
    for (int i = 0; i < 32; i++) {
        int idx = tid * 32 + i;
        el[i] = topk_idx[idx];
        atomicAdd(&h[el[i]], 1);
    }
    __syncthreads();
    if (tid == 0) {
        int s = 0;
        for (int e = 0; e < E_N; e++) { offs[e] = s; cnt[e] = h[e]; base[e] = s; s += h[e]; }
        offs[E_N] = s;
    }
    __syncthreads();
    if (tid < 8) h[tid] = base[tid];
    __syncthreads();
#pragma unroll
    for (int i = 0; i < 32; i++) {
        int idx = tid * 32 + i;
        int e = el[i];
        int pos = atomicAdd(&h[e], 1);
        assign_tok[pos] = idx >> 1;
        assign_e[pos] = e;
        slot[idx] = pos;
    }
}

// ---------------- persistent grouped GEMM, 128x128, 4 waves, m97 K-loop -----
// B from pre-swizzled 16KB tiles [e][NT][KT] (linear image copy); A staged
// with inverse-swizzled source column. Expert->XCD pinning e = bid&7.

template<bool GATHER, bool EPI>
__global__ __launch_bounds__(256, 4) void k_gemm(
    const unsigned short* __restrict__ A,
    const unsigned short* __restrict__ BT,   // tiled
    const float* __restrict__ bias,
    unsigned short* __restrict__ C,
    const int* __restrict__ cnt, const int* __restrict__ offs,
    const int* __restrict__ gather_tok,
    int Kslice, int N, int ldA, int NT, int KT, int GX, int KS, size_t slicePitch)
{
    __shared__ __align__(1024) char lds[32768];   // A 16KB | B 16KB

    int bid = blockIdx.x;
    int e = bid & 7;                 // expert == XCD
    int lb = bid >> 3;
    int M = cnt[e];
    if (M <= 0) return;
    int off_e = offs[e];
    int nrows = (M + 127) >> 7;
    int ntiles = nrows * GX * KS;

    int tid = threadIdx.x;
    int wv = tid >> 6, lane = tid & 63;
    int lr = lane & 15, hi = lane >> 4;
    int mW = (wv >> 1) * 64, nW = (wv & 1) * 64;
    int colsw = ((lane & 7) ^ (lane >> 3)) * 8;
    int l3 = lane >> 3;
    int nt = Kslice >> 6;

    for (int t = lb; t < ntiles; t += NBX) {
        int r = t % nrows;
        int q = t / nrows;
        int xn = q % GX;
        int ks = q / GX;
        int m0 = r * 128;
        int n0 = xn * 128;
        int kbase = ks * Kslice;

        const unsigned short* aptr[4];
        const unsigned short* bptr[4];
        size_t btile = ((size_t)(e * NT + xn) * KT + (size_t)ks * nt) * 8192;
#pragma unroll
        for (int i = 0; i < 4; i++) {
            int j = wv * 4 + i;
            int rr = m0 + j * 8 + l3; rr = (rr < M) ? rr : (M - 1);
            size_t arow = GATHER ? (size_t)gather_tok[off_e + rr] : (size_t)(off_e + rr);
            aptr[i] = A + arow * (size_t)ldA + kbase + colsw;
            bptr[i] = BT + btile + j * 512 + lane * 8;   // linear tile image
        }

        f32x4 acc[4][4];
        f32x4 zz = {0.f, 0.f, 0.f, 0.f};
#pragma unroll
        for (int mi = 0; mi < 4; mi++)
#pragma unroll
            for (int ni = 0; ni < 4; ni++) acc[mi][ni] = zz;

        for (int kt = 0; kt < nt; ++kt) {
            __syncthreads();                  // prev tile fully consumed
#pragma unroll
            for (int i = 0; i < 4; i++) {
                gload16(aptr[i] + kt * 64, (unsigned short*)(lds + (wv * 4 + i) * 1024));
                gload16(bptr[i] + (size_t)kt * 8192,
                        (unsigned short*)(lds + 16384 + (wv * 4 + i) * 1024));
            }
            __syncthreads();                  // drains vmcnt before barrier
#pragma unroll
            for (int kss = 0; kss < 2; kss++) {
                int cb = (kss * 64 + hi * 16) ^ ((lr & 7) << 4);
                short8 afr[4], bfr[4];
#pragma unroll
                for (int ni = 0; ni < 4; ni++)
                    bfr[ni] = *(const short8*)(lds + 16384 + (nW + ni * 16 + lr) * 128 + cb);
#pragma unroll
                for (int mi = 0; mi < 4; mi++)
                    afr[mi] = *(const short8*)(lds + (mW + mi * 16 + lr) * 128 + cb);
                __builtin_amdgcn_s_setprio(1);
#pragma unroll
                for (int mi = 0; mi < 4; mi++)
#pragma unroll
                    for (int ni = 0; ni < 4; ni++)
                        acc[mi][ni] = __builtin_amdgcn_mfma_f32_16x16x32_bf16(
                            afr[mi], bfr[ni], acc[mi][ni], 0, 0, 0);
                __builtin_amdgcn_s_setprio(0);
            }
        }

        unsigned short* Cs = C + ks * slicePitch;
        float bv[4] = {0.f, 0.f, 0.f, 0.f};
        if (EPI) {
#pragma unroll
            for (int ni = 0; ni < 4; ni++)
                bv[ni] = bias[(size_t)e * N + (n0 + nW + ni * 16 + lr)];
        }
#pragma unroll
        for (int mi = 0; mi < 4; mi++) {
            int mb = m0 + mW + mi * 16 + hi * 4;
#pragma unroll
            for (int rr = 0; rr < 4; rr++) {
                int m = mb + rr;
                if (m < M) {
                    unsigned short* crow = Cs + (size_t)(off_e + m) * N;
#pragma unroll
                    for (int ni = 0; ni < 4; ni++) {
                        float v = acc[mi][ni][rr];
                        if (EPI) v = fmaxf(v + bv[ni], 0.0f);
                        crow[n0 + nW + ni * 16 + lr] = f2bf(v);
                    }
                }
            }
        }
    }
}

// ---------------- LN1 over F, in-place ----------------

__global__ __launch_bounds__(256) void k_ln1(unsigned short* __restrict__ H,
        const float* __restrict__ g, const float* __restrict__ b,
        const int* __restrict__ assign_e)
{
    size_t a = blockIdx.x;
    int e = assign_e[a];
    unsigned short* row = H + a * FF;
    int tid = threadIdx.x;
    uint4 u0 = *(const uint4*)(row + tid * 16);
    uint4 u1 = *(const uint4*)(row + tid * 16 + 8);
    float v[16];
    unp(u0.x, v[0], v[1]);  unp(u0.y, v[2], v[3]);
    unp(u0.z, v[4], v[5]);  unp(u0.w, v[6], v[7]);
    unp(u1.x, v[8], v[9]);  unp(u1.y, v[10], v[11]);
    unp(u1.z, v[12], v[13]); unp(u1.w, v[14], v[15]);
    float s = 0.f, q = 0.f;
#pragma unroll
    for (int i = 0; i < 16; i++) { s += v[i]; q += v[i] * v[i]; }
#pragma unroll
    for (int off = 32; off; off >>= 1) { s += __shfl_xor(s, off); q += __shfl_xor(q, off); }
    __shared__ float red[8];
    int wv = tid >> 6, lane = tid & 63;
    if (lane == 0) { red[wv * 2] = s; red[wv * 2 + 1] = q; }
    __syncthreads();
    s = red[0] + red[2] + red[4] + red[6];
    q = red[1] + red[3] + red[5] + red[7];
    float mu = s * (1.0f / FF);
    float var = q * (1.0f / FF) - mu * mu;
    float rstd = rsqrtf(var + LN_EPS);
    const float* gg = g + (size_t)e * FF + tid * 16;
    const float* bb = b + (size_t)e * FF + tid * 16;
    float4 G0 = *(const float4*)(gg);      float4 G1 = *(const float4*)(gg + 4);
    float4 G2 = *(const float4*)(gg + 8);  float4 G3 = *(const float4*)(gg + 12);
    float4 B0 = *(const float4*)(bb);      float4 B1 = *(const float4*)(bb + 4);
    float4 B2 = *(const float4*)(bb + 8);  float4 B3 = *(const float4*)(bb + 12);
    float gvv[16] = {G0.x,G0.y,G0.z,G0.w,G1.x,G1.y,G1.z,G1.w,G2.x,G2.y,G2.z,G2.w,G3.x,G3.y,G3.z,G3.w};
    float bvv[16] = {B0.x,B0.y,B0.z,B0.w,B1.x,B1.y,B1.z,B1.w,B2.x,B2.y,B2.z,B2.w,B3.x,B3.y,B3.z,B3.w};
#pragma unroll
    for (int i = 0; i < 16; i++) v[i] = (v[i] - mu) * rstd * gvv[i] + bvv[i];
    u0.x = pk(v[0], v[1]);  u0.y = pk(v[2], v[3]);
    u0.z = pk(v[4], v[5]);  u0.w = pk(v[6], v[7]);
    u1.x = pk(v[8], v[9]);  u1.y = pk(v[10], v[11]);
    u1.z = pk(v[12], v[13]); u1.w = pk(v[14], v[15]);
    *(uint4*)(row + tid * 16) = u0;
    *(uint4*)(row + tid * 16 + 8) = u1;
}

// ---------------- combine: sum split-K partials + bias + relu + LN2 + gate --

__global__ __launch_bounds__(256) void k_comb(const unsigned short* __restrict__ Yp,
        const float* __restrict__ g, const float* __restrict__ b2,
        const float* __restrict__ be,
        const int* __restrict__ slot, const float* __restrict__ topk_p,
        const int* __restrict__ assign_e, float* __restrict__ out)
{
    int t = blockIdx.x;
    int s0 = slot[2 * t], s1 = slot[2 * t + 1];
    float p0 = topk_p[2 * t], p1 = topk_p[2 * t + 1];
    int e0 = assign_e[s0], e1 = assign_e[s1];
    int tid = threadIdx.x;
    int d = tid * 4;
    const unsigned short* Y1 = Yp + (size_t)NA * DM;
    uint2 ua0 = *(const uint2*)(Yp + (size_t)s0 * DM + d);
    uint2 ua1 = *(const uint2*)(Y1 + (size_t)s0 * DM + d);
    uint2 ub0 = *(const uint2*)(Yp + (size_t)s1 * DM + d);
    uint2 ub1 = *(const uint2*)(Y1 + (size_t)s1 * DM + d);
    float4 bza = *(const float4*)(b2 + (size_t)e0 * DM + d);
    float4 bzb = *(const float4*)(b2 + (size_t)e1 * DM + d);
    float x0, x1, y0, y1;
    float va[4], vb[4];
    unp(ua0.x, x0, x1); unp(ua1.x, y0, y1);
    va[0] = fmaxf(x0 + y0 + bza.x, 0.f); va[1] = fmaxf(x1 + y1 + bza.y, 0.f);
    unp(ua0.y, x0, x1); unp(ua1.y, y0, y1);
    va[2] = fmaxf(x0 + y0 + bza.z, 0.f); va[3] = fmaxf(x1 + y1 + bza.w, 0.f);
    unp(ub0.x, x0, x1); unp(ub1.x, y0, y1);
    vb[0] = fmaxf(x0 + y0 + bzb.x, 0.f); vb[1] = fmaxf(x1 + y1 + bzb.y, 0.f);
    unp(ub0.y, x0, x1); unp(ub1.y, y0, y1);
    vb[2] = fmaxf(x0 + y0 + bzb.z, 0.f); vb[3] = fmaxf(x1 + y1 + bzb.w, 0.f);

    float sa = 0.f, qa = 0.f, sb = 0.f, qb = 0.f;
#pragma unroll
    for (int i = 0; i < 4; i++) {
        sa += va[i]; qa += va[i] * va[i];
        sb += vb[i]; qb += vb[i] * vb[i];
    }
#pragma unroll
    for (int off = 32; off; off >>= 1) {
        sa += __shfl_xor(sa, off); qa += __shfl_xor(qa, off);
        sb += __shfl_xor(sb, off); qb += __shfl_xor(qb, off);
    }
    __shared__ float red[16];
    int wv = tid >> 6, lane = tid & 63;
    if (lane == 0) { red[wv*4+0]=sa; red[wv*4+1]=qa; red[wv*4+2]=sb; red[wv*4+3]=qb; }
    __syncthreads();
    sa = red[0] + red[4] + red[8]  + red[12];
    qa = red[1] + red[5] + red[9]  + red[13];
    sb = red[2] + red[6] + red[10] + red[14];
    qb = red[3] + red[7] + red[11] + red[15];
    float mua = sa * (1.0f / DM), vara = qa * (1.0f / DM) - mua * mua;
    float ra = rsqrtf(vara + LN_EPS);
    float mub = sb * (1.0f / DM), varb = qb * (1.0f / DM) - mub * mub;
    float rb = rsqrtf(varb + LN_EPS);
    float4 ga  = *(const float4*)(g + (size_t)e0 * DM + d);
    float4 ba  = *(const float4*)(be + (size_t)e0 * DM + d);
    float4 gb4 = *(const float4*)(g + (size_t)e1 * DM + d);
    float4 bb4 = *(const float4*)(be + (size_t)e1 * DM + d);
    float4 o;
    o.x = p0 * ((va[0] - mua) * ra * ga.x + ba.x) + p1 * ((vb[0] - mub) * rb * gb4.x + bb4.x);
    o.y = p0 * ((va[1] - mua) * ra * ga.y + ba.y) + p1 * ((vb[1] - mub) * rb * gb4.y + bb4.y);
    o.z = p0 * ((va[2] - mua) * ra * ga.z + ba.z) + p1 * ((vb[2] - mub) * rb * gb4.z + bb4.z);
    o.w = p0 * ((va[3] - mua) * ra * ga.w + ba.w) + p1 * ((vb[3] - mub) * rb * gb4.w + bb4.w);
    *(float4*)(out + (size_t)t * DM + d) = o;
}

// ---------------- launch ----------------

extern "C" void kernel_launch(void* const* d_in, const int* in_sizes, int n_in,
                              void* d_out, int out_size, void* d_ws, size_t ws_size,
                              hipStream_t stream) {
    const float* x   = (const float*)d_in[0];
    const float* Wr  = (const float*)d_in[1];
    const float* br  = (const float*)d_in[2];
    const float* W1  = (const float*)d_in[3];
    const float* b1  = (const float*)d_in[4];
    const float* g1  = (const float*)d_in[5];
    const float* be1 = (const float*)d_in[6];
    const float* W2  = (const float*)d_in[7];
    const float* b2  = (const float*)d_in[8];
    const float* g2  = (const float*)d_in[9];
    const float* be2 = (const float*)d_in[10];
    float* out = (float*)d_out;

    char* w = (char*)d_ws;
    int*   cnt        = (int*)(w);
    int*   offs       = (int*)(w + 128);
    int*   topk_idx   = (int*)(w + 512);
    float* topk_p     = (float*)(w + 512 + (32 << 10));
    int*   assign_tok = (int*)(w + 512 + (64 << 10));
    int*   assign_e   = (int*)(w + 512 + (96 << 10));
    int*   slot       = (int*)(w + 512 + (128 << 10));
    unsigned short* xb  = (unsigned short*)(w + ((size_t)1 << 20));
    unsigned short* W1T = (unsigned short*)(w + ((size_t)9 << 20));    // tiled, 64MB
    unsigned short* W2T = (unsigned short*)(w + ((size_t)73 << 20));   // tiled, 64MB
    unsigned short* Hb  = (unsigned short*)(w + ((size_t)137 << 20));  // [NA][F] bf16
    unsigned short* Yp  = (unsigned short*)(w + ((size_t)201 << 20));  // [2][NA][D] bf16

    // prep: flat grid — 4096 W1 tiles, 4096 W2 tiles, 1024 router blocks
    k_prep<<<9216, 256, 0, stream>>>(
        W1, W2, W1T, W2T, x, Wr, br, xb, topk_idx, topk_p);
    k_route2<<<1, 256, 0, stream>>>(topk_idx, cnt, offs, assign_tok, assign_e, slot);
    // GEMM1: gathered x rows x W1T(tiled) -> Hb(+bias,relu); K=1024, NT=32 KT=16
    k_gemm<true, true><<<8 * NBX, 256, 0, stream>>>(
        xb, W1T, b1, Hb, cnt, offs, assign_tok, DM, FF, DM, 32, 16, 32, 1, 0);
    k_ln1<<<NA, 256, 0, stream>>>(Hb, g1, be1, assign_e);
    // GEMM2: Hb x W2T(tiled) -> Yp partials; Kslice=2048, NT=8 KT=64, KS=2
    k_gemm<false, false><<<8 * NBX, 256, 0, stream>>>(
        Hb, W2T, nullptr, Yp, cnt, offs, nullptr, FF / 2, DM, FF, 8, 64, 8, 2,
        (size_t)NA * DM);
    k_comb<<<NTOK, 256, 0, stream>>>(Yp, g2, b2, be2, slot, topk_p, assign_e, out);
}